// Round 1
// baseline (209.921 us; speedup 1.0000x reference)
//
#include <hip/hip_runtime.h>

using f32x4 = __attribute__((ext_vector_type(4))) float;
using s16x8 = __attribute__((ext_vector_type(8))) short;
using s16x4 = __attribute__((ext_vector_type(4))) short;

#define P_PIX 196
#define PPAD  208
#define LDK   72   // LDS row stride in shorts (64 + 8 pad)
#define KT    64

static __device__ __forceinline__ short f2bf(float f) {
  union { float f; unsigned u; } a; a.f = f;
  unsigned u = a.u;
  u += 0x7fffu + ((u >> 16) & 1u);   // round-to-nearest-even
  return (short)(u >> 16);
}

static __device__ __forceinline__ f32x4 mfma16(s16x8 a, s16x8 b, f32x4 c) {
  return __builtin_amdgcn_mfma_f32_16x16x32_bf16(a, b, c, 0, 0, 0);
}

// stage A tile: 128 rows x 64 k (bf16 weights), src row stride Ktot
static __device__ __forceinline__ void stageA(const short* __restrict__ src, int Ktot,
                                              int k0, short* lA, int tid) {
  #pragma unroll
  for (int it = 0; it < 4; ++it) {
    int t = it * 256 + tid;
    int r = t >> 3, ck = t & 7;
    s16x8 v = *reinterpret_cast<const s16x8*>(src + r * Ktot + k0 + ck * 8);
    *reinterpret_cast<s16x8*>(lA + r * LDK + ck * 8) = v;
  }
}

// stage B tile from bf16 pixel-major [p][C]: rows p in [0,196), k slice [k0,k0+64)
static __device__ __forceinline__ void stageB(const short* __restrict__ src, int C,
                                              int k0, short* lB, int tid) {
  for (int t = tid; t < P_PIX * 8; t += 256) {
    int p = t >> 3, ck = t & 7;
    s16x8 v = *reinterpret_cast<const s16x8*>(src + p * C + k0 + ck * 8);
    *reinterpret_cast<s16x8*>(lB + p * LDK + ck * 8) = v;
  }
}

// ---------------- prep kernels ----------------

__global__ void k_cvt(const float* __restrict__ src, short* __restrict__ dst, int n) {
  int i = blockIdx.x * 256 + threadIdx.x;
  if (i < n) dst[i] = f2bf(src[i]);
}

// w2 (256,256,3,3) -> W2t[s][co][ci], s = dy*3+dx
__global__ void k_w2t(const float* __restrict__ w2, short* __restrict__ W2t) {
  int i = blockIdx.x * 256 + threadIdx.x;
  if (i < 9 * 256 * 256) {
    int s = i >> 16, rem = i & 65535;
    int co = rem >> 8, ci = rem & 255;
    W2t[i] = f2bf(w2[(co * 256 + ci) * 9 + s]);
  }
}

__global__ void k_bn(const float* g1, const float* b1, const float* m1, const float* v1,
                     const float* g2, const float* b2, const float* m2, const float* v2,
                     const float* g3, const float* b3, const float* m3, const float* v3,
                     float* bn) {
  int t = blockIdx.x * 256 + threadIdx.x;
  if (t < 256) {
    float inv = g1[t] * rsqrtf(v1[t] + 1e-5f);
    bn[t] = inv; bn[256 + t] = b1[t] - m1[t] * inv;
  } else if (t < 512) {
    int c = t - 256;
    float inv = g2[c] * rsqrtf(v2[c] + 1e-5f);
    bn[512 + c] = inv; bn[768 + c] = b2[c] - m2[c] * inv;
  } else if (t < 1536) {
    int c = t - 512;
    float inv = g3[c] * rsqrtf(v3[c] + 1e-5f);
    bn[1024 + c] = inv; bn[2048 + c] = b3[c] - m3[c] * inv;
  }
}

// ---------------- layer 1: 1x1, 1024->256, (y+1)^2, BN ----------------

__global__ __launch_bounds__(256) void k_layer1(
    const float* __restrict__ x, const short* __restrict__ W1b,
    const float* __restrict__ bnbuf, short* __restrict__ H1) {
  __shared__ __align__(16) short lA[128 * LDK];
  __shared__ __align__(16) short lB[PPAD * LDK];
  const int tid = threadIdx.x;
  const int n = blockIdx.x >> 1;
  const int mb = blockIdx.x & 1;
  const int lane = tid & 63, wave = tid >> 6;
  const int l15 = lane & 15, l4 = lane >> 4;

  for (int t = tid; t < 12 * LDK; t += 256) lB[P_PIX * LDK + t] = (short)0;

  f32x4 zero = {0.f, 0.f, 0.f, 0.f};
  f32x4 acc[2][13];
  #pragma unroll
  for (int m = 0; m < 2; ++m)
    #pragma unroll
    for (int j = 0; j < 13; ++j) acc[m][j] = zero;

  const float* xs = x + (size_t)n * 1024 * P_PIX;
  const short* Asrc = W1b + mb * 128 * 1024;

  for (int kt = 0; kt < 16; ++kt) {
    __syncthreads();
    stageA(Asrc, 1024, kt * KT, lA, tid);
    // transposed stage of fp32 x: [ci][p] -> LDS [p][ci], converted to bf16
    for (int t = tid; t < 784; t += 256) {
      int pg = t % 49, kg = t / 49;
      const float* sp = xs + (size_t)(kt * KT + kg * 4) * P_PIX + pg * 4;
      f32x4 v0 = *reinterpret_cast<const f32x4*>(sp);
      f32x4 v1 = *reinterpret_cast<const f32x4*>(sp + P_PIX);
      f32x4 v2 = *reinterpret_cast<const f32x4*>(sp + 2 * P_PIX);
      f32x4 v3 = *reinterpret_cast<const f32x4*>(sp + 3 * P_PIX);
      #pragma unroll
      for (int q = 0; q < 4; ++q) {
        s16x4 w;
        w[0] = f2bf(v0[q]); w[1] = f2bf(v1[q]);
        w[2] = f2bf(v2[q]); w[3] = f2bf(v3[q]);
        *reinterpret_cast<s16x4*>(lB + (pg * 4 + q) * LDK + kg * 4) = w;
      }
    }
    __syncthreads();
    #pragma unroll
    for (int kk = 0; kk < 2; ++kk) {
      s16x8 a0 = *reinterpret_cast<const s16x8*>(lA + (wave * 32 + l15) * LDK + kk * 32 + l4 * 8);
      s16x8 a1 = *reinterpret_cast<const s16x8*>(lA + (wave * 32 + 16 + l15) * LDK + kk * 32 + l4 * 8);
      #pragma unroll
      for (int j = 0; j < 13; ++j) {
        s16x8 b = *reinterpret_cast<const s16x8*>(lB + (j * 16 + l15) * LDK + kk * 32 + l4 * 8);
        acc[0][j] = mfma16(a0, b, acc[0][j]);
        acc[1][j] = mfma16(a1, b, acc[1][j]);
      }
    }
  }

  short* Hn = H1 + (size_t)n * P_PIX * 256;
  #pragma unroll
  for (int m = 0; m < 2; ++m) {
    int co = mb * 128 + wave * 32 + m * 16 + l4 * 4;
    f32x4 sc = *reinterpret_cast<const f32x4*>(bnbuf + co);
    f32x4 sh = *reinterpret_cast<const f32x4*>(bnbuf + 256 + co);
    #pragma unroll
    for (int j = 0; j < 13; ++j) {
      int p = j * 16 + l15;
      if (p < P_PIX) {
        s16x4 o;
        #pragma unroll
        for (int i = 0; i < 4; ++i) {
          float y = acc[m][j][i] + 1.0f;
          o[i] = f2bf(y * y * sc[i] + sh[i]);
        }
        *reinterpret_cast<s16x4*>(Hn + p * 256 + co) = o;
      }
    }
  }
}

// ---------------- layer 2: 3x3 pad 1, 256->256, (y+1)^2, BN ----------------

__global__ __launch_bounds__(256) void k_layer2(
    const short* __restrict__ H1, const short* __restrict__ W2t,
    const float* __restrict__ bnbuf, short* __restrict__ H2) {
  __shared__ __align__(16) short lA[128 * LDK];
  __shared__ __align__(16) short lB[PPAD * LDK];
  const int tid = threadIdx.x;
  const int n = blockIdx.x >> 1;
  const int mb = blockIdx.x & 1;
  const int lane = tid & 63, wave = tid >> 6;
  const int l15 = lane & 15, l4 = lane >> 4;

  for (int t = tid; t < 12 * LDK; t += 256) lB[P_PIX * LDK + t] = (short)0;

  // validity bits per j-tile for this lane: bit dy (0..2): h+dy-1 in [0,14); bit 3+dx: w+dx-1 in [0,14)
  int vmask[13];
  #pragma unroll
  for (int j = 0; j < 13; ++j) {
    int p = j * 16 + l15;
    int h = p / 14, w = p % 14;
    int m = 16;                 // dx=1 always valid (w in [0,14))
    if (h >= 1)  m |= 1;
    if (h < 14)  m |= 2;
    if (h < 13)  m |= 4;
    if (w >= 1)  m |= 8;
    if (w < 13)  m |= 32;
    vmask[j] = m;
  }

  f32x4 zero = {0.f, 0.f, 0.f, 0.f};
  f32x4 acc[2][13];
  #pragma unroll
  for (int m = 0; m < 2; ++m)
    #pragma unroll
    for (int j = 0; j < 13; ++j) acc[m][j] = zero;

  const short* Bsrc = H1 + (size_t)n * P_PIX * 256;

  for (int kt = 0; kt < 4; ++kt) {
    __syncthreads();                       // protect lB from previous compute
    stageB(Bsrc, 256, kt * KT, lB, tid);
    for (int s = 0; s < 9; ++s) {
      __syncthreads();                     // lA safe to restage; lB visible (s==0)
      stageA(W2t + (size_t)(s * 256 + mb * 128) * 256, 256, kt * KT, lA, tid);
      __syncthreads();
      int dy = s / 3, dx = s % 3;
      int doff = (dy - 1) * 14 + (dx - 1);
      #pragma unroll
      for (int kk = 0; kk < 2; ++kk) {
        s16x8 a0 = *reinterpret_cast<const s16x8*>(lA + (wave * 32 + l15) * LDK + kk * 32 + l4 * 8);
        s16x8 a1 = *reinterpret_cast<const s16x8*>(lA + (wave * 32 + 16 + l15) * LDK + kk * 32 + l4 * 8);
        #pragma unroll
        for (int j = 0; j < 13; ++j) {
          int p = j * 16 + l15;
          bool valid = ((vmask[j] >> dy) & 1) && ((vmask[j] >> (3 + dx)) & 1);
          int row = valid ? (p + doff) : P_PIX;   // row 196 is zero-filled
          s16x8 b = *reinterpret_cast<const s16x8*>(lB + row * LDK + kk * 32 + l4 * 8);
          acc[0][j] = mfma16(a0, b, acc[0][j]);
          acc[1][j] = mfma16(a1, b, acc[1][j]);
        }
      }
    }
  }

  short* Hn = H2 + (size_t)n * P_PIX * 256;
  #pragma unroll
  for (int m = 0; m < 2; ++m) {
    int co = mb * 128 + wave * 32 + m * 16 + l4 * 4;
    f32x4 sc = *reinterpret_cast<const f32x4*>(bnbuf + 512 + co);
    f32x4 sh = *reinterpret_cast<const f32x4*>(bnbuf + 768 + co);
    #pragma unroll
    for (int j = 0; j < 13; ++j) {
      int p = j * 16 + l15;
      if (p < P_PIX) {
        s16x4 o;
        #pragma unroll
        for (int i = 0; i < 4; ++i) {
          float y = acc[m][j][i] + 1.0f;
          o[i] = f2bf(y * y * sc[i] + sh[i]);
        }
        *reinterpret_cast<s16x4*>(Hn + p * 256 + co) = o;
      }
    }
  }
}

// ---------------- layer 3: 1x1, 256->1024, (y+1)^2, BN, + residual ----------------

__global__ __launch_bounds__(256) void k_layer3(
    const short* __restrict__ H2, const short* __restrict__ W3b,
    const float* __restrict__ bnbuf, const float* __restrict__ x,
    float* __restrict__ out) {
  __shared__ __align__(16) short lA[128 * LDK];
  __shared__ __align__(16) short lB[PPAD * LDK];
  const int tid = threadIdx.x;
  const int n = blockIdx.x >> 3;
  const int mb = blockIdx.x & 7;
  const int lane = tid & 63, wave = tid >> 6;
  const int l15 = lane & 15, l4 = lane >> 4;

  for (int t = tid; t < 12 * LDK; t += 256) lB[P_PIX * LDK + t] = (short)0;

  f32x4 zero = {0.f, 0.f, 0.f, 0.f};
  f32x4 acc[2][13];
  #pragma unroll
  for (int m = 0; m < 2; ++m)
    #pragma unroll
    for (int j = 0; j < 13; ++j) acc[m][j] = zero;

  const short* Bsrc = H2 + (size_t)n * P_PIX * 256;
  const short* Asrc = W3b + (size_t)mb * 128 * 256;

  for (int kt = 0; kt < 4; ++kt) {
    __syncthreads();
    stageA(Asrc, 256, kt * KT, lA, tid);
    stageB(Bsrc, 256, kt * KT, lB, tid);
    __syncthreads();
    #pragma unroll
    for (int kk = 0; kk < 2; ++kk) {
      s16x8 a0 = *reinterpret_cast<const s16x8*>(lA + (wave * 32 + l15) * LDK + kk * 32 + l4 * 8);
      s16x8 a1 = *reinterpret_cast<const s16x8*>(lA + (wave * 32 + 16 + l15) * LDK + kk * 32 + l4 * 8);
      #pragma unroll
      for (int j = 0; j < 13; ++j) {
        s16x8 b = *reinterpret_cast<const s16x8*>(lB + (j * 16 + l15) * LDK + kk * 32 + l4 * 8);
        acc[0][j] = mfma16(a0, b, acc[0][j]);
        acc[1][j] = mfma16(a1, b, acc[1][j]);
      }
    }
  }

  #pragma unroll
  for (int m = 0; m < 2; ++m) {
    int co = mb * 128 + wave * 32 + m * 16 + l4 * 4;   // in [0,1024)
    f32x4 sc = *reinterpret_cast<const f32x4*>(bnbuf + 1024 + co);
    f32x4 sh = *reinterpret_cast<const f32x4*>(bnbuf + 2048 + co);
    #pragma unroll
    for (int j = 0; j < 13; ++j) {
      int p = j * 16 + l15;
      if (p < P_PIX) {
        #pragma unroll
        for (int i = 0; i < 4; ++i) {
          size_t idx = ((size_t)(n * 1024 + co + i)) * P_PIX + p;
          float y = acc[m][j][i] + 1.0f;
          out[idx] = y * y * sc[i] + sh[i] + x[idx];
        }
      }
    }
  }
}

// ---------------- launch ----------------

extern "C" void kernel_launch(void* const* d_in, const int* in_sizes, int n_in,
                              void* d_out, int out_size, void* d_ws, size_t ws_size,
                              hipStream_t stream) {
  (void)in_sizes; (void)n_in; (void)out_size; (void)ws_size;
  const float* x  = (const float*)d_in[0];
  const float* w1 = (const float*)d_in[1];
  const float* w2 = (const float*)d_in[2];
  const float* w3 = (const float*)d_in[3];
  const float* g1 = (const float*)d_in[4];
  const float* b1 = (const float*)d_in[5];
  const float* m1 = (const float*)d_in[6];
  const float* v1 = (const float*)d_in[7];
  const float* g2 = (const float*)d_in[8];
  const float* b2 = (const float*)d_in[9];
  const float* m2 = (const float*)d_in[10];
  const float* v2 = (const float*)d_in[11];
  const float* g3 = (const float*)d_in[12];
  const float* b3 = (const float*)d_in[13];
  const float* m3 = (const float*)d_in[14];
  const float* v3 = (const float*)d_in[15];

  char* ws = (char*)d_ws;
  short* W1b  = (short*)(ws + 0);          // 256*1024*2        = 524288
  short* W2t  = (short*)(ws + 524288);     // 9*256*256*2       = 1179648
  short* W3b  = (short*)(ws + 1703936);    // 1024*256*2        = 524288
  float* bnbuf= (float*)(ws + 2228224);    // 3072 floats       = 12288
  short* H1   = (short*)(ws + 2240512);    // 128*196*256*2     = 12845056
  short* H2   = (short*)(ws + 15085568);   // 128*196*256*2     = 12845056  (end 27930624)

  k_cvt<<<1024, 256, 0, stream>>>(w1, W1b, 256 * 1024);
  k_cvt<<<1024, 256, 0, stream>>>(w3, W3b, 1024 * 256);
  k_w2t<<<2304, 256, 0, stream>>>(w2, W2t);
  k_bn<<<6, 256, 0, stream>>>(g1, b1, m1, v1, g2, b2, m2, v2, g3, b3, m3, v3, bnbuf);

  k_layer1<<<256, 256, 0, stream>>>(x, W1b, bnbuf, H1);
  k_layer2<<<256, 256, 0, stream>>>(H1, W2t, bnbuf, H2);
  k_layer3<<<1024, 256, 0, stream>>>(H2, W3b, bnbuf, x, (float*)d_out);
}

// Round 2
// 190.201 us; speedup vs baseline: 1.1037x; 1.1037x over previous
//
#include <hip/hip_runtime.h>

using f32x4 = __attribute__((ext_vector_type(4))) float;
using s16x8 = __attribute__((ext_vector_type(8))) short;
using s16x4 = __attribute__((ext_vector_type(4))) short;

#define P_PIX 196
#define NROW  208      // B-tile rows (13 * 16)
#define KT    32       // shorts per LDS row = 64 B = 4 chunks of 16 B

static __device__ __forceinline__ short f2bf(float f) {
  union { float f; unsigned u; } a; a.f = f;
  unsigned u = a.u;
  u += 0x7fffu + ((u >> 16) & 1u);   // round-to-nearest-even
  return (short)(u >> 16);
}

static __device__ __forceinline__ f32x4 mfma16(s16x8 a, s16x8 b, f32x4 c) {
  return __builtin_amdgcn_mfma_f32_16x16x32_bf16(a, b, c, 0, 0, 0);
}

// async global->LDS, 16 B per lane; dest must be lane-linear (base + lane*16)
static __device__ __forceinline__ void gload16(const short* g, short* l) {
  __builtin_amdgcn_global_load_lds(
      (const __attribute__((address_space(1))) unsigned int*)(g),
      (__attribute__((address_space(3))) unsigned int*)(l), 16, 0, 0);
}

// swizzled 16B-fragment pointer: chunk = l4 ^ ((row>>1)&3)
static __device__ __forceinline__ const s16x8* fragp(const short* buf, int row, int l4) {
  return (const s16x8*)(buf + row * KT + ((l4 ^ ((row >> 1) & 3)) << 3));
}

// stage `rows` rows x 32 shorts (k offset k0, row stride srcK shorts) into LDS.
// dest linear (gload_lds requirement); SOURCE chunk pre-swizzled to match fragp.
// row index clamped to rmax (tail tiles: garbage data, masked at C-write).
static __device__ __forceinline__ void stage(const short* __restrict__ src, int srcK,
                                             int k0, short* dst, int rows, int rmax,
                                             int tid) {
  for (int t = tid; t < rows * 4; t += 256) {
    int r = t >> 2, c = t & 3;
    int rr = r < rmax ? r : rmax;
    int cs = c ^ ((r >> 1) & 3);
    gload16(src + (size_t)rr * srcK + k0 + cs * 8, dst + t * 8);
  }
}

// ---------------- prep kernels ----------------

__global__ void k_cvt(const float* __restrict__ src, short* __restrict__ dst, int n) {
  int i = blockIdx.x * 256 + threadIdx.x;
  if (i < n) dst[i] = f2bf(src[i]);
}

// w2 (256,256,3,3) -> W2t[s][co][ci], s = dy*3+dx
__global__ void k_w2t(const float* __restrict__ w2, short* __restrict__ W2t) {
  int i = blockIdx.x * 256 + threadIdx.x;
  if (i < 9 * 256 * 256) {
    int s = i >> 16, rem = i & 65535;
    int co = rem >> 8, ci = rem & 255;
    W2t[i] = f2bf(w2[(co * 256 + ci) * 9 + s]);
  }
}

__global__ void k_bn(const float* g1, const float* b1, const float* m1, const float* v1,
                     const float* g2, const float* b2, const float* m2, const float* v2,
                     const float* g3, const float* b3, const float* m3, const float* v3,
                     float* bn) {
  int t = blockIdx.x * 256 + threadIdx.x;
  if (t < 256) {
    float inv = g1[t] * rsqrtf(v1[t] + 1e-5f);
    bn[t] = inv; bn[256 + t] = b1[t] - m1[t] * inv;
  } else if (t < 512) {
    int c = t - 256;
    float inv = g2[c] * rsqrtf(v2[c] + 1e-5f);
    bn[512 + c] = inv; bn[768 + c] = b2[c] - m2[c] * inv;
  } else if (t < 1536) {
    int c = t - 512;
    float inv = g3[c] * rsqrtf(v3[c] + 1e-5f);
    bn[1024 + c] = inv; bn[2048 + c] = b3[c] - m3[c] * inv;
  }
}

// ---------------- layer 1: 1x1, 1024->256 ----------------
// grid: n(128) x mb(2). B staged from fp32 x via regs (issue-early / write-late).

__global__ __launch_bounds__(256) void k_layer1(
    const float* __restrict__ x, const short* __restrict__ W1b,
    const float* __restrict__ bnbuf, short* __restrict__ H1) {
  __shared__ __align__(16) short lA[2][128 * KT];
  __shared__ __align__(16) short lB[2][NROW * KT];
  const int tid = threadIdx.x;
  const int n = blockIdx.x >> 1, mb = blockIdx.x & 1;
  const int lane = tid & 63, wave = tid >> 6;
  const int l15 = lane & 15, l4 = lane >> 4;

  // zero rows 196..207 of both lB buffers (j=12 tail reads; never restaged)
  if (tid < 96) {
    int b = tid / 48, idx = tid % 48;
    s16x8 z = {0,0,0,0,0,0,0,0};
    *(s16x8*)(&lB[b][196 * KT + idx * 8]) = z;
  }

  const float* xs = x + (size_t)n * 1024 * P_PIX;
  const short* Asrc = W1b + (size_t)mb * 128 * 1024;

  // x prefetch: tasks (pg 0..48 -> 4 pixels, kg 0..7 -> 4 ci); thread owns t0, t1
  f32x4 ra[4], rb[4];
  const int t0 = tid, t1 = tid + 256;
  const int pg0 = t0 % 49, kg0 = t0 / 49;
  const int pg1 = t1 % 49, kg1 = t1 / 49;
  const bool has1 = (t1 < 392);

  auto loadx = [&](int kt) {
    const float* sp0 = xs + (size_t)(kt * 32 + kg0 * 4) * P_PIX + pg0 * 4;
    ra[0] = *(const f32x4*)sp0;
    ra[1] = *(const f32x4*)(sp0 + P_PIX);
    ra[2] = *(const f32x4*)(sp0 + 2 * P_PIX);
    ra[3] = *(const f32x4*)(sp0 + 3 * P_PIX);
    if (has1) {
      const float* sp1 = xs + (size_t)(kt * 32 + kg1 * 4) * P_PIX + pg1 * 4;
      rb[0] = *(const f32x4*)sp1;
      rb[1] = *(const f32x4*)(sp1 + P_PIX);
      rb[2] = *(const f32x4*)(sp1 + 2 * P_PIX);
      rb[3] = *(const f32x4*)(sp1 + 3 * P_PIX);
    }
  };
  auto cvt1 = [&](const f32x4* r, int pg, int kg, short* buf) {
    int chunk = kg >> 1, inner = (kg & 1) * 4;
    #pragma unroll
    for (int q = 0; q < 4; ++q) {
      int p = pg * 4 + q;
      s16x4 w;
      w[0] = f2bf(r[0][q]); w[1] = f2bf(r[1][q]);
      w[2] = f2bf(r[2][q]); w[3] = f2bf(r[3][q]);
      *(s16x4*)(buf + p * KT + ((chunk ^ ((p >> 1) & 3)) << 3) + inner) = w;
    }
  };
  auto cvtw = [&](short* buf) {
    cvt1(ra, pg0, kg0, buf);
    if (has1) cvt1(rb, pg1, kg1, buf);
  };

  f32x4 acc[2][13];
  f32x4 zero = {0.f, 0.f, 0.f, 0.f};
  #pragma unroll
  for (int m = 0; m < 2; ++m)
    #pragma unroll
    for (int j = 0; j < 13; ++j) acc[m][j] = zero;

  // prologue
  stage(Asrc, 1024, 0, lA[0], 128, 127, tid);
  loadx(0);
  cvtw(lB[0]);
  __syncthreads();

  for (int kt = 0; kt < 32; ++kt) {
    const int cur = kt & 1, nxt = cur ^ 1;
    if (kt < 31) {
      stage(Asrc, 1024, (kt + 1) * 32, lA[nxt], 128, 127, tid);
      loadx(kt + 1);
    }
    const short* A = lA[cur];
    const short* B = lB[cur];
    s16x8 a0 = *fragp(A, wave * 32 + l15, l4);
    s16x8 a1 = *fragp(A, wave * 32 + 16 + l15, l4);
    #pragma unroll
    for (int j = 0; j < 13; ++j) {
      s16x8 b = *fragp(B, j * 16 + l15, l4);
      acc[0][j] = mfma16(a0, b, acc[0][j]);
      acc[1][j] = mfma16(a1, b, acc[1][j]);
    }
    if (kt < 31) cvtw(lB[nxt]);
    __syncthreads();
  }

  short* Hn = H1 + (size_t)n * P_PIX * 256;
  #pragma unroll
  for (int m = 0; m < 2; ++m) {
    int co = mb * 128 + wave * 32 + m * 16 + l4 * 4;
    f32x4 sc = *(const f32x4*)(bnbuf + co);
    f32x4 sh = *(const f32x4*)(bnbuf + 256 + co);
    #pragma unroll
    for (int j = 0; j < 13; ++j) {
      int p = j * 16 + l15;
      if (p < P_PIX) {
        s16x4 o;
        #pragma unroll
        for (int i = 0; i < 4; ++i) {
          float y = acc[m][j][i] + 1.0f;
          o[i] = f2bf(y * y * sc[i] + sh[i]);
        }
        *(s16x4*)(Hn + p * 256 + co) = o;
      }
    }
  }
}

// ---------------- layer 2: 3x3 pad 1, 256->256 ----------------
// grid: n(128) x mb(2) x jh(2). jh=0: j 0..6, jh=1: j 6..12 (j=6 written by jh=0).
// one barrier per (kt,s); lA dbuf per s, lB dbuf per kt.

__global__ __launch_bounds__(256) void k_layer2(
    const short* __restrict__ H1, const short* __restrict__ W2t,
    const float* __restrict__ bnbuf, short* __restrict__ H2) {
  __shared__ __align__(16) short lA[2][128 * KT];
  __shared__ __align__(16) short lB[2][NROW * KT];
  const int tid = threadIdx.x;
  const int bi = blockIdx.x;
  const int n = bi >> 2, mb = (bi >> 1) & 1, jh = bi & 1;
  const int lane = tid & 63, wave = tid >> 6;
  const int l15 = lane & 15, l4 = lane >> 4;

  if (tid < 96) {
    int b = tid / 48, idx = tid % 48;
    s16x8 z = {0,0,0,0,0,0,0,0};
    *(s16x8*)(&lB[b][196 * KT + idx * 8]) = z;
  }

  // validity bits for this lane's 7 j-frags
  int vm[7];
  #pragma unroll
  for (int jj = 0; jj < 7; ++jj) {
    int j = jh * 6 + jj;
    int p = j * 16 + l15;
    int m = 0;
    if (p < P_PIX) {
      int h = p / 14, w = p % 14;
      m = 2 | 16;                    // dy=1, dx=1 always valid
      if (h >= 1)  m |= 1;
      if (h < 13)  m |= 4;
      if (w >= 1)  m |= 8;
      if (w < 13)  m |= 32;
    }
    vm[jj] = m;
  }

  f32x4 acc[2][7];
  f32x4 zero = {0.f, 0.f, 0.f, 0.f};
  #pragma unroll
  for (int m = 0; m < 2; ++m)
    #pragma unroll
    for (int jj = 0; jj < 7; ++jj) acc[m][jj] = zero;

  const short* Bsrc = H1 + (size_t)n * P_PIX * 256;

  // prologue: lA for g=0 (s=0,kt=0), lB for kt=0
  stage(W2t + (size_t)(mb * 128) * 256, 256, 0, lA[0], 128, 127, tid);
  stage(Bsrc, 256, 0, lB[0], P_PIX, P_PIX - 1, tid);
  __syncthreads();

  for (int g = 0; g < 72; ++g) {
    const int kt = g / 9, s = g % 9;
    if (g < 71) {
      const int g1 = g + 1, kt1 = g1 / 9, s1 = g1 % 9;
      stage(W2t + (size_t)(s1 * 256 + mb * 128) * 256, 256, kt1 * 32,
            lA[g1 & 1], 128, 127, tid);
    }
    if (s == 0 && kt < 7)
      stage(Bsrc, 256, (kt + 1) * 32, lB[(kt + 1) & 1], P_PIX, P_PIX - 1, tid);

    const short* A = lA[g & 1];
    const short* B = lB[kt & 1];
    const int dy = s / 3, dx = s % 3;
    const int doff = (dy - 1) * 14 + (dx - 1);
    s16x8 a0 = *fragp(A, wave * 32 + l15, l4);
    s16x8 a1 = *fragp(A, wave * 32 + 16 + l15, l4);
    #pragma unroll
    for (int jj = 0; jj < 7; ++jj) {
      int j = jh * 6 + jj;
      int p = j * 16 + l15;
      bool valid = ((vm[jj] >> dy) & 1) && ((vm[jj] >> (3 + dx)) & 1);
      int row = valid ? (p + doff) : P_PIX;   // row 196 is zero
      s16x8 b = *fragp(B, row, l4);
      acc[0][jj] = mfma16(a0, b, acc[0][jj]);
      acc[1][jj] = mfma16(a1, b, acc[1][jj]);
    }
    __syncthreads();
  }

  short* Hn = H2 + (size_t)n * P_PIX * 256;
  #pragma unroll
  for (int m = 0; m < 2; ++m) {
    int co = mb * 128 + wave * 32 + m * 16 + l4 * 4;
    f32x4 sc = *(const f32x4*)(bnbuf + 512 + co);
    f32x4 sh = *(const f32x4*)(bnbuf + 768 + co);
    #pragma unroll
    for (int jj = 0; jj < 7; ++jj) {
      if (jh && jj == 0) continue;           // j=6 owned by jh=0
      int p = (jh * 6 + jj) * 16 + l15;
      if (p < P_PIX) {
        s16x4 o;
        #pragma unroll
        for (int i = 0; i < 4; ++i) {
          float y = acc[m][jj][i] + 1.0f;
          o[i] = f2bf(y * y * sc[i] + sh[i]);
        }
        *(s16x4*)(Hn + p * 256 + co) = o;
      }
    }
  }
}

// ---------------- layer 3: 1x1, 256->1024, + residual ----------------
// grid: tile(121, flattened pixels) x mb(8)

__global__ __launch_bounds__(256) void k_layer3(
    const short* __restrict__ H2, const short* __restrict__ W3b,
    const float* __restrict__ bnbuf, const float* __restrict__ x,
    float* __restrict__ out) {
  __shared__ __align__(16) short lA[2][128 * KT];
  __shared__ __align__(16) short lB[2][NROW * KT];
  const int tid = threadIdx.x;
  const int tile = blockIdx.x >> 3, mb = blockIdx.x & 7;
  const int lane = tid & 63, wave = tid >> 6;
  const int l15 = lane & 15, l4 = lane >> 4;
  const int P0 = tile * NROW;
  const int rmax = 128 * P_PIX - 1 - P0;   // clamp row for tail tile

  const short* Asrc = W3b + (size_t)mb * 128 * 256;
  const short* Bsrc = H2 + (size_t)P0 * 256;

  f32x4 acc[2][13];
  f32x4 zero = {0.f, 0.f, 0.f, 0.f};
  #pragma unroll
  for (int m = 0; m < 2; ++m)
    #pragma unroll
    for (int j = 0; j < 13; ++j) acc[m][j] = zero;

  stage(Asrc, 256, 0, lA[0], 128, 127, tid);
  stage(Bsrc, 256, 0, lB[0], NROW, rmax, tid);
  __syncthreads();

  for (int kt = 0; kt < 8; ++kt) {
    const int cur = kt & 1, nxt = cur ^ 1;
    if (kt < 7) {
      stage(Asrc, 256, (kt + 1) * 32, lA[nxt], 128, 127, tid);
      stage(Bsrc, 256, (kt + 1) * 32, lB[nxt], NROW, rmax, tid);
    }
    const short* A = lA[cur];
    const short* B = lB[cur];
    s16x8 a0 = *fragp(A, wave * 32 + l15, l4);
    s16x8 a1 = *fragp(A, wave * 32 + 16 + l15, l4);
    #pragma unroll
    for (int j = 0; j < 13; ++j) {
      s16x8 b = *fragp(B, j * 16 + l15, l4);
      acc[0][j] = mfma16(a0, b, acc[0][j]);
      acc[1][j] = mfma16(a1, b, acc[1][j]);
    }
    __syncthreads();
  }

  #pragma unroll
  for (int m = 0; m < 2; ++m) {
    int co = mb * 128 + wave * 32 + m * 16 + l4 * 4;
    f32x4 sc = *(const f32x4*)(bnbuf + 1024 + co);
    f32x4 sh = *(const f32x4*)(bnbuf + 2048 + co);
    #pragma unroll
    for (int j = 0; j < 13; ++j) {
      int P = P0 + j * 16 + l15;
      if (P < 128 * P_PIX) {
        int n = P / P_PIX, p = P - n * P_PIX;
        size_t base = ((size_t)n * 1024 + co) * P_PIX + p;
        #pragma unroll
        for (int i = 0; i < 4; ++i) {
          float y = acc[m][j][i] + 1.0f;
          out[base + (size_t)i * P_PIX] = y * y * sc[i] + sh[i] + x[base + (size_t)i * P_PIX];
        }
      }
    }
  }
}

// ---------------- launch ----------------

extern "C" void kernel_launch(void* const* d_in, const int* in_sizes, int n_in,
                              void* d_out, int out_size, void* d_ws, size_t ws_size,
                              hipStream_t stream) {
  (void)in_sizes; (void)n_in; (void)out_size; (void)ws_size;
  const float* x  = (const float*)d_in[0];
  const float* w1 = (const float*)d_in[1];
  const float* w2 = (const float*)d_in[2];
  const float* w3 = (const float*)d_in[3];
  const float* g1 = (const float*)d_in[4];
  const float* b1 = (const float*)d_in[5];
  const float* m1 = (const float*)d_in[6];
  const float* v1 = (const float*)d_in[7];
  const float* g2 = (const float*)d_in[8];
  const float* b2 = (const float*)d_in[9];
  const float* m2 = (const float*)d_in[10];
  const float* v2 = (const float*)d_in[11];
  const float* g3 = (const float*)d_in[12];
  const float* b3 = (const float*)d_in[13];
  const float* m3 = (const float*)d_in[14];
  const float* v3 = (const float*)d_in[15];

  char* ws = (char*)d_ws;
  short* W1b   = (short*)(ws + 0);          // 256*1024*2   = 524288
  short* W2t   = (short*)(ws + 524288);     // 9*256*256*2  = 1179648
  short* W3b   = (short*)(ws + 1703936);    // 1024*256*2   = 524288
  float* bnbuf = (float*)(ws + 2228224);    // 3072 floats  = 12288
  short* H1    = (short*)(ws + 2240512);    // 128*196*256*2 = 12845056
  short* H2    = (short*)(ws + 15085568);   // 128*196*256*2 = 12845056

  k_cvt<<<1024, 256, 0, stream>>>(w1, W1b, 256 * 1024);
  k_cvt<<<1024, 256, 0, stream>>>(w3, W3b, 1024 * 256);
  k_w2t<<<2304, 256, 0, stream>>>(w2, W2t);
  k_bn<<<6, 256, 0, stream>>>(g1, b1, m1, v1, g2, b2, m2, v2, g3, b3, m3, v3, bnbuf);

  k_layer1<<<256, 256, 0, stream>>>(x, W1b, bnbuf, H1);
  k_layer2<<<512, 256, 0, stream>>>(H1, W2t, bnbuf, H2);
  k_layer3<<<968, 256, 0, stream>>>(H2, W3b, bnbuf, x, (float*)d_out);
}

// Round 4
// 169.141 us; speedup vs baseline: 1.2411x; 1.1245x over previous
//
#include <hip/hip_runtime.h>

using f32x4 = __attribute__((ext_vector_type(4))) float;
using s16x8 = __attribute__((ext_vector_type(8))) short;
using s16x4 = __attribute__((ext_vector_type(4))) short;

#define P_PIX 196
#define NPIX_ALL (128 * 196)   // 25088
#define NROW  208
#define KT    32               // shorts per LDS row = 64 B = 4 chunks of 16 B

static __device__ __forceinline__ short f2bf(float f) {
  union { float f; unsigned u; } a; a.f = f;
  unsigned u = a.u;
  u += 0x7fffu + ((u >> 16) & 1u);   // RNE
  return (short)(u >> 16);
}

static __device__ __forceinline__ f32x4 mfma16(s16x8 a, s16x8 b, f32x4 c) {
  return __builtin_amdgcn_mfma_f32_16x16x32_bf16(a, b, c, 0, 0, 0);
}

static __device__ __forceinline__ void gload16(const short* g, short* l) {
  __builtin_amdgcn_global_load_lds(
      (const __attribute__((address_space(1))) unsigned int*)(g),
      (__attribute__((address_space(3))) unsigned int*)(l), 16, 0, 0);
}

// swizzled 16B-fragment pointer: chunk = l4 ^ ((row>>1)&3)
static __device__ __forceinline__ const s16x8* fragp(const short* buf, int row, int l4) {
  return (const s16x8*)(buf + row * KT + ((l4 ^ ((row >> 1) & 3)) << 3));
}

// stage rows x 32 shorts into LDS; dest linear, source chunk pre-swizzled.
static __device__ __forceinline__ void stage(const short* __restrict__ src, int srcK,
                                             int k0, short* dst, int rows, int rmax,
                                             int tid) {
  for (int t = tid; t < rows * 4; t += 256) {
    int r = t >> 2, c = t & 3;
    int rr = r < rmax ? r : rmax;
    int cs = c ^ ((r >> 1) & 3);
    gload16(src + (size_t)rr * srcK + k0 + cs * 8, dst + t * 8);
  }
}

// ---------------- prep kernels ----------------

__global__ void k_cvt4(const float* __restrict__ src, short* __restrict__ dst, int n4) {
  int i = blockIdx.x * 256 + threadIdx.x;
  if (i < n4) {
    f32x4 v = *(const f32x4*)(src + i * 4);
    s16x4 o;
    o[0] = f2bf(v[0]); o[1] = f2bf(v[1]); o[2] = f2bf(v[2]); o[3] = f2bf(v[3]);
    *(s16x4*)(dst + i * 4) = o;
  }
}

// w2 (256,256,3,3) -> W2t[s][co][ci]
__global__ void k_w2t(const float* __restrict__ w2, short* __restrict__ W2t) {
  int i = blockIdx.x * 256 + threadIdx.x;
  if (i < 9 * 256 * 256) {
    int s = i >> 16, rem = i & 65535;
    int co = rem >> 8, ci = rem & 255;
    W2t[i] = f2bf(w2[(co * 256 + ci) * 9 + s]);
  }
}

__global__ void k_bn(const float* g1, const float* b1, const float* m1, const float* v1,
                     const float* g2, const float* b2, const float* m2, const float* v2,
                     const float* g3, const float* b3, const float* m3, const float* v3,
                     float* bn) {
  int t = blockIdx.x * 256 + threadIdx.x;
  if (t < 256) {
    float inv = g1[t] * rsqrtf(v1[t] + 1e-5f);
    bn[t] = inv; bn[256 + t] = b1[t] - m1[t] * inv;
  } else if (t < 512) {
    int c = t - 256;
    float inv = g2[c] * rsqrtf(v2[c] + 1e-5f);
    bn[512 + c] = inv; bn[768 + c] = b2[c] - m2[c] * inv;
  } else if (t < 1536) {
    int c = t - 512;
    float inv = g3[c] * rsqrtf(v3[c] + 1e-5f);
    bn[1024 + c] = inv; bn[2048 + c] = b3[c] - m3[c] * inv;
  }
}

// ---------------- layer 1: 1x1, 1024->256 ----------------
// grid: n(128) x mb(2) x jh(2).  A-frags from global (W1 L2-resident).
// x staged via regs, 2-deep prefetch; LDS = B dbuf only (16 KB), 128 local rows.

__global__ __launch_bounds__(256) void k_layer1(
    const float* __restrict__ x, const short* __restrict__ W1b,
    const float* __restrict__ bnbuf, short* __restrict__ H1) {
  __shared__ __align__(16) short lB[2][128 * KT];
  const int tid = threadIdx.x;
  const int b = blockIdx.x;
  const int n = b >> 2, mb = (b >> 1) & 1, jh = b & 1;
  const int lane = tid & 63, wave = tid >> 6;
  const int l15 = lane & 15, l4 = lane >> 4;

  // jh=1: local rows 100..111 (p 196..207) must be zero in both buffers
  if (jh == 1 && tid < 96) {
    int bb = tid / 48, idx = tid % 48;
    s16x8 z = {0,0,0,0,0,0,0,0};
    *(s16x8*)(&lB[bb][100 * KT + idx * 8]) = z;
  }

  const float* xs = x + (size_t)n * 1024 * P_PIX;
  const short* Asrc = W1b + (size_t)(mb * 128) * 1024;

  const int npg = jh ? 25 : 28;
  const int pgbase = jh ? 24 : 0;
  const bool act = tid < npg * 8;
  const int pg = pgbase + (act ? tid % npg : 0);
  const int kg = act ? tid / npg : 0;
  const int lrow0 = pg * 4 - jh * 96;   // local row of first pixel

  f32x4 rX[4], rY[4];
  auto loadx = [&](int kt, f32x4* r) {
    if (!act) return;
    const float* sp = xs + (size_t)(kt * 32 + kg * 4) * P_PIX + pg * 4;
    r[0] = *(const f32x4*)sp;
    r[1] = *(const f32x4*)(sp + P_PIX);
    r[2] = *(const f32x4*)(sp + 2 * P_PIX);
    r[3] = *(const f32x4*)(sp + 3 * P_PIX);
  };
  auto cvtw = [&](const f32x4* r, short* buf) {
    if (!act) return;
    int chunk = kg >> 1, inner = (kg & 1) * 4;
    #pragma unroll
    for (int q = 0; q < 4; ++q) {
      int lr = lrow0 + q;
      s16x4 w;
      w[0] = f2bf(r[0][q]); w[1] = f2bf(r[1][q]);
      w[2] = f2bf(r[2][q]); w[3] = f2bf(r[3][q]);
      *(s16x4*)(buf + lr * KT + ((chunk ^ ((lr >> 1) & 3)) << 3) + inner) = w;
    }
  };

  f32x4 acc[2][7];
  f32x4 zero = {0.f, 0.f, 0.f, 0.f};
  #pragma unroll
  for (int m = 0; m < 2; ++m)
    #pragma unroll
    for (int jj = 0; jj < 7; ++jj) acc[m][jj] = zero;

  loadx(0, rX);
  loadx(1, rY);
  cvtw(rX, lB[0]);
  __syncthreads();

  auto body = [&](int kt, f32x4* rNext, f32x4* rFill) {
    // entering: lB[kt&1] holds tile kt; rNext holds x(kt+1)
    if (kt + 2 < 32) loadx(kt + 2, rFill);
    s16x8 a0 = *(const s16x8*)(Asrc + (size_t)(wave * 32 + l15) * 1024 + kt * 32 + l4 * 8);
    s16x8 a1 = *(const s16x8*)(Asrc + (size_t)(wave * 32 + 16 + l15) * 1024 + kt * 32 + l4 * 8);
    const short* B = lB[kt & 1];
    #pragma unroll
    for (int jj = 0; jj < 7; ++jj) {
      s16x8 bfr = *fragp(B, jj * 16 + l15, l4);
      acc[0][jj] = mfma16(a0, bfr, acc[0][jj]);
      acc[1][jj] = mfma16(a1, bfr, acc[1][jj]);
    }
    if (kt + 1 < 32) cvtw(rNext, lB[(kt + 1) & 1]);
    __syncthreads();
  };

  for (int kt = 0; kt < 32; kt += 2) {
    body(kt, rY, rX);       // fills rX = x(kt+2), consumes rY
    body(kt + 1, rX, rY);   // fills rY = x(kt+3), consumes rX
  }

  short* Hn = H1 + (size_t)n * P_PIX * 256;
  #pragma unroll
  for (int m = 0; m < 2; ++m) {
    int co = mb * 128 + wave * 32 + m * 16 + l4 * 4;
    f32x4 sc = *(const f32x4*)(bnbuf + co);
    f32x4 sh = *(const f32x4*)(bnbuf + 256 + co);
    #pragma unroll
    for (int jj = 0; jj < 7; ++jj) {
      if (jh && jj == 0) continue;          // j=6 owned by jh=0
      int p = (jh * 6 + jj) * 16 + l15;
      if (p < P_PIX) {
        s16x4 o;
        #pragma unroll
        for (int i = 0; i < 4; ++i) {
          float y = acc[m][jj][i] + 1.0f;
          o[i] = f2bf(y * y * sc[i] + sh[i]);
        }
        *(s16x4*)(Hn + p * 256 + co) = o;
      }
    }
  }
}

// ---------------- layer 2: 3x3 pad 1, 256->256 ----------------
// grid: n(128) x mb(2) x jh(2). A-frags from global (W2t L2-resident).
// lB dbuf per kt; ONE barrier per kt. K=256 -> kt 0..7 (8 tiles of 32).

__global__ __launch_bounds__(256) void k_layer2(
    const short* __restrict__ H1, const short* __restrict__ W2t,
    const float* __restrict__ bnbuf, short* __restrict__ H2) {
  __shared__ __align__(16) short lB[2][NROW * KT];
  const int tid = threadIdx.x;
  const int b = blockIdx.x;
  const int n = b >> 2, mb = (b >> 1) & 1, jh = b & 1;
  const int lane = tid & 63, wave = tid >> 6;
  const int l15 = lane & 15, l4 = lane >> 4;

  if (tid < 8) {   // zero row 196 in both buffers
    int bb = tid >> 2, idx = tid & 3;
    s16x8 z = {0,0,0,0,0,0,0,0};
    *(s16x8*)(&lB[bb][196 * KT + idx * 8]) = z;
  }

  int vm[7];
  #pragma unroll
  for (int jj = 0; jj < 7; ++jj) {
    int p = (jh * 6 + jj) * 16 + l15;
    int m = 0;
    if (p < P_PIX) {
      int h = p / 14, w = p % 14;
      m = 2 | 16;
      if (h >= 1)  m |= 1;
      if (h < 13)  m |= 4;
      if (w >= 1)  m |= 8;
      if (w < 13)  m |= 32;
    }
    vm[jj] = m;
  }

  f32x4 acc[2][7];
  f32x4 zero = {0.f, 0.f, 0.f, 0.f};
  #pragma unroll
  for (int m = 0; m < 2; ++m)
    #pragma unroll
    for (int jj = 0; jj < 7; ++jj) acc[m][jj] = zero;

  const short* Bsrc = H1 + (size_t)n * P_PIX * 256;

  stage(Bsrc, 256, 0, lB[0], P_PIX, P_PIX - 1, tid);
  __syncthreads();

  for (int kt = 0; kt < 8; ++kt) {          // FIX: full K=256 (was kt<4)
    if (kt < 7)                              // FIX: stage guard (was kt<3)
      stage(Bsrc, 256, (kt + 1) * 32, lB[(kt + 1) & 1], P_PIX, P_PIX - 1, tid);
    const short* B = lB[kt & 1];
    #pragma unroll
    for (int s = 0; s < 9; ++s) {
      const int dy = s / 3, dx = s % 3;
      const int doff = (dy - 1) * 14 + (dx - 1);
      const size_t arow = (size_t)(s * 256 + mb * 128 + wave * 32 + l15) * 256 + kt * 32 + l4 * 8;
      s16x8 a0 = *(const s16x8*)(W2t + arow);
      s16x8 a1 = *(const s16x8*)(W2t + arow + 16 * 256);
      #pragma unroll
      for (int jj = 0; jj < 7; ++jj) {
        int p = (jh * 6 + jj) * 16 + l15;
        bool valid = ((vm[jj] >> dy) & 1) && ((vm[jj] >> (3 + dx)) & 1);
        int row = valid ? (p + doff) : 196;
        s16x8 bfr = *fragp(B, row, l4);
        acc[0][jj] = mfma16(a0, bfr, acc[0][jj]);
        acc[1][jj] = mfma16(a1, bfr, acc[1][jj]);
      }
    }
    __syncthreads();
  }

  short* Hn = H2 + (size_t)n * P_PIX * 256;
  #pragma unroll
  for (int m = 0; m < 2; ++m) {
    int co = mb * 128 + wave * 32 + m * 16 + l4 * 4;
    f32x4 sc = *(const f32x4*)(bnbuf + 512 + co);
    f32x4 sh = *(const f32x4*)(bnbuf + 768 + co);
    #pragma unroll
    for (int jj = 0; jj < 7; ++jj) {
      if (jh && jj == 0) continue;
      int p = (jh * 6 + jj) * 16 + l15;
      if (p < P_PIX) {
        s16x4 o;
        #pragma unroll
        for (int i = 0; i < 4; ++i) {
          float y = acc[m][jj][i] + 1.0f;
          o[i] = f2bf(y * y * sc[i] + sh[i]);
        }
        *(s16x4*)(Hn + p * 256 + co) = o;
      }
    }
  }
}

// ---------------- layer 3: 1x1, 256->1024, + residual ----------------
// grid: tile(121) x mb(16), M=64 per block. A-frags from global.
// Epilogue: 3 batches of register-buffered x loads, then compute+store.

__global__ __launch_bounds__(256) void k_layer3(
    const short* __restrict__ H2, const short* __restrict__ W3b,
    const float* __restrict__ bnbuf, const float* __restrict__ x,
    float* __restrict__ out) {
  __shared__ __align__(16) short lB[2][NROW * KT];
  const int tid = threadIdx.x;
  const int tile = blockIdx.x >> 4, mb = blockIdx.x & 15;
  const int lane = tid & 63, wave = tid >> 6;
  const int l15 = lane & 15, l4 = lane >> 4;
  const int P0 = tile * NROW;
  const int rmax = NPIX_ALL - 1 - P0;

  const short* Asrc = W3b + (size_t)(mb * 64) * 256;
  const short* Bsrc = H2 + (size_t)P0 * 256;

  f32x4 acc[13];
  f32x4 zero = {0.f, 0.f, 0.f, 0.f};
  #pragma unroll
  for (int j = 0; j < 13; ++j) acc[j] = zero;

  stage(Bsrc, 256, 0, lB[0], NROW, rmax, tid);
  __syncthreads();

  for (int kt = 0; kt < 8; ++kt) {
    if (kt < 7)
      stage(Bsrc, 256, (kt + 1) * 32, lB[(kt + 1) & 1], NROW, rmax, tid);
    s16x8 a = *(const s16x8*)(Asrc + (size_t)(wave * 16 + l15) * 256 + kt * 32 + l4 * 8);
    const short* B = lB[kt & 1];
    #pragma unroll
    for (int j = 0; j < 13; ++j) {
      s16x8 bfr = *fragp(B, j * 16 + l15, l4);
      acc[j] = mfma16(a, bfr, acc[j]);
    }
    __syncthreads();
  }

  const int co = mb * 64 + wave * 16 + l4 * 4;
  f32x4 sc = *(const f32x4*)(bnbuf + 1024 + co);
  f32x4 sh = *(const f32x4*)(bnbuf + 2048 + co);

  // batches: j = [0..4], [5..8], [9..12]
  #pragma unroll
  for (int bb = 0; bb < 3; ++bb) {
    const int jb = (bb == 0) ? 0 : (bb == 1 ? 5 : 9);
    const int jn = (bb == 0) ? 5 : 4;
    float xv[5][4];
    size_t bidx[5];
    bool okv[5];
    #pragma unroll
    for (int jj = 0; jj < 5; ++jj) {
      if (jj >= jn) break;
      int j = jb + jj;
      int P = P0 + j * 16 + l15;
      bool ok = P < NPIX_ALL;
      int nn = P / P_PIX, pp = P - nn * P_PIX;
      size_t bidxj = ((size_t)(nn * 1024 + co)) * P_PIX + pp;
      bidx[jj] = bidxj; okv[jj] = ok;
      #pragma unroll
      for (int i = 0; i < 4; ++i)
        xv[jj][i] = ok ? x[bidxj + (size_t)i * P_PIX] : 0.f;
    }
    #pragma unroll
    for (int jj = 0; jj < 5; ++jj) {
      if (jj >= jn) break;
      int j = jb + jj;
      if (okv[jj]) {
        #pragma unroll
        for (int i = 0; i < 4; ++i) {
          float y = acc[j][i] + 1.0f;
          out[bidx[jj] + (size_t)i * P_PIX] = y * y * sc[i] + sh[i] + xv[jj][i];
        }
      }
    }
  }
}

// ---------------- launch ----------------

extern "C" void kernel_launch(void* const* d_in, const int* in_sizes, int n_in,
                              void* d_out, int out_size, void* d_ws, size_t ws_size,
                              hipStream_t stream) {
  (void)in_sizes; (void)n_in; (void)out_size; (void)ws_size;
  const float* x  = (const float*)d_in[0];
  const float* w1 = (const float*)d_in[1];
  const float* w2 = (const float*)d_in[2];
  const float* w3 = (const float*)d_in[3];
  const float* g1 = (const float*)d_in[4];
  const float* b1 = (const float*)d_in[5];
  const float* m1 = (const float*)d_in[6];
  const float* v1 = (const float*)d_in[7];
  const float* g2 = (const float*)d_in[8];
  const float* b2 = (const float*)d_in[9];
  const float* m2 = (const float*)d_in[10];
  const float* v2 = (const float*)d_in[11];
  const float* g3 = (const float*)d_in[12];
  const float* b3 = (const float*)d_in[13];
  const float* m3 = (const float*)d_in[14];
  const float* v3 = (const float*)d_in[15];

  char* ws = (char*)d_ws;
  short* W1b   = (short*)(ws + 0);          // 256*1024*2   = 524288
  short* W2t   = (short*)(ws + 524288);     // 9*256*256*2  = 1179648
  short* W3b   = (short*)(ws + 1703936);    // 1024*256*2   = 524288
  float* bnbuf = (float*)(ws + 2228224);    // 3072 floats  = 12288
  short* H1    = (short*)(ws + 2240512);    // 128*196*256*2 = 12845056
  short* H2    = (short*)(ws + 15085568);   // 128*196*256*2 = 12845056

  k_cvt4<<<256, 256, 0, stream>>>(w1, W1b, 256 * 1024 / 4);
  k_cvt4<<<256, 256, 0, stream>>>(w3, W3b, 1024 * 256 / 4);
  k_w2t<<<2304, 256, 0, stream>>>(w2, W2t);
  k_bn<<<6, 256, 0, stream>>>(g1, b1, m1, v1, g2, b2, m2, v2, g3, b3, m3, v3, bnbuf);

  k_layer1<<<512, 256, 0, stream>>>(x, W1b, bnbuf, H1);
  k_layer2<<<512, 256, 0, stream>>>(H1, W2t, bnbuf, H2);
  k_layer3<<<1936, 256, 0, stream>>>(H2, W3b, bnbuf, x, (float*)d_out);
}